// Round 4
// baseline (487.346 us; speedup 1.0000x reference)
//
#include <hip/hip_runtime.h>

#define Bn 512
#define Tn 1024
#define Nn 64
#define NB (Bn / 2)   // 256 blocks: one wave handles batches b and b+NB

typedef _Float16 h2 __attribute__((ext_vector_type(2)));
typedef _Float16 h8 __attribute__((ext_vector_type(8)));

#if __has_builtin(__builtin_amdgcn_fdot2)
__device__ __forceinline__ float fdot2f(h2 a, h2 b, float c) {
    return __builtin_amdgcn_fdot2(a, b, c, false);
}
#else
__device__ __forceinline__ float fdot2f(h2 a, h2 b, float c) {
    return fmaf((float)a[0], (float)b[0], fmaf((float)a[1], (float)b[1], c));
}
#endif

__device__ __forceinline__ float wave_sum(float v) {
#pragma unroll
    for (int off = 32; off >= 1; off >>= 1) v += __shfl_xor(v, off, 64);
    return v;
}

// One wave, TWO independent CRF chains interleaved. The serial dependency
// (p -> LDS broadcast -> dot -> u') is ~300+ cyc of latency per step; round 3
// showed the wave stalls ~70% of each step. Two chains share the E-matrix
// registers and overlap each other's stalls.
__global__ __launch_bounds__(64) void crf_dual(
    const float* __restrict__ emit,
    const int*   __restrict__ target,
    const int*   __restrict__ mask,
    const float* __restrict__ trans,
    const float* __restrict__ strans,
    const float* __restrict__ etrans,
    float*       __restrict__ out)
{
    __shared__ __align__(16) _Float16 pbuf[2 * Nn];   // [0..63] chain A, [64..127] chain B

    const int lane = threadIdx.x;
    const int bA = blockIdx.x;
    const int bB = blockIdx.x + NB;

    // E column j (j = lane) as fp16 pairs over i — shared by both chains
    h2 E2[32];
#pragma unroll
    for (int m = 0; m < 32; ++m) {
        float x0 = trans[(2 * m) * Nn + lane];
        float x1 = trans[(2 * m + 1) * Nn + lane];
        h2 e; e[0] = (_Float16)__expf(x0); e[1] = (_Float16)__expf(x1);
        E2[m] = e;
    }

    // both lengths in one packed shuffle reduction (each sum <= 1024 < 2^16)
    const int* mrA = mask + (size_t)bA * Tn;
    const int* mrB = mask + (size_t)bB * Tn;
    int ls = 0;
#pragma unroll
    for (int k = 0; k < Tn / Nn; ++k)
        ls += mrA[k * Nn + lane] + (mrB[k * Nn + lane] << 16);
#pragma unroll
    for (int off = 32; off >= 1; off >>= 1) ls += __shfl_xor(ls, off, 64);
    const int lenA = ls & 0xffff;
    const int lenB = ls >> 16;
    const int lmax = lenA > lenB ? lenA : lenB;

    const size_t eA = (size_t)bA * Tn * Nn;
    const size_t eB = (size_t)bB * Tn * Nn;

    // u_0 = exp(strans) for both chains; exact pow2 rescale sums in SA/SB
    float uuA = __expf(strans[lane]);
    float uuB = uuA;
    int SA = 0, SB = 0;

    // per-chain w pipeline: wC*[q] = exp(emit row (t0-1)+q); eN* = raw next rows
    float wCA[8], wCB[8], eNA[8], eNB[8];
#pragma unroll
    for (int q = 0; q < 8; ++q) { wCA[q] = emit[eA + (size_t)q * Nn + lane];
                                  wCB[q] = emit[eB + (size_t)q * Nn + lane]; }
#pragma unroll
    for (int q = 0; q < 8; ++q) { eNA[q] = emit[eA + (size_t)(8 + q) * Nn + lane];
                                  eNB[q] = emit[eB + (size_t)(8 + q) * Nn + lane]; }
#pragma unroll
    for (int q = 0; q < 8; ++q) { wCA[q] = __expf(wCA[q]); wCB[q] = __expf(wCB[q]); }

    auto superstep = [&](int t, float wA, float wB) {
        // front-ends (independent, interleave freely)
        int ba = __builtin_amdgcn_readfirstlane(__float_as_int(uuA));
        int bb = __builtin_amdgcn_readfirstlane(__float_as_int(uuB));
        int mkA = 127 - ((ba >> 23) & 0xff);
        int mkB = 127 - ((bb >> 23) & 0xff);
        float pA = ldexpf(uuA, mkA) * wA;     // p in (0, ~1300) -> fp16 safe
        float pB = ldexpf(uuB, mkB) * wB;
        pbuf[lane]      = (_Float16)pA;
        pbuf[Nn + lane] = (_Float16)pB;

        const h8* p8 = (const h8*)pbuf;       // broadcast b128 reads, in-order DS pipe
        float a0 = 0.f, a1 = 0.f, a2 = 0.f, a3 = 0.f;
        float b0 = 0.f, b1 = 0.f, b2 = 0.f, b3 = 0.f;
#pragma unroll
        for (int r = 0; r < 8; ++r) {
            h8 va = p8[r];
            h8 vb = p8[8 + r];
            a0 = fdot2f(__builtin_shufflevector(va, va, 0, 1), E2[4 * r + 0], a0);
            a1 = fdot2f(__builtin_shufflevector(va, va, 2, 3), E2[4 * r + 1], a1);
            a2 = fdot2f(__builtin_shufflevector(va, va, 4, 5), E2[4 * r + 2], a2);
            a3 = fdot2f(__builtin_shufflevector(va, va, 6, 7), E2[4 * r + 3], a3);
            b0 = fdot2f(__builtin_shufflevector(vb, vb, 0, 1), E2[4 * r + 0], b0);
            b1 = fdot2f(__builtin_shufflevector(vb, vb, 2, 3), E2[4 * r + 1], b1);
            b2 = fdot2f(__builtin_shufflevector(vb, vb, 4, 5), E2[4 * r + 2], b2);
            b3 = fdot2f(__builtin_shufflevector(vb, vb, 6, 7), E2[4 * r + 3], b3);
        }
        float dA = (a0 + a1) + (a2 + a3);
        float dB = (b0 + b1) + (b2 + b3);
        // commit guards (wave-uniform): freeze chain past its own length
        if (t < lenA) { uuA = dA; SA += mkA; }
        if (t < lenB) { uuB = dB; SB += mkB; }
    };

    int t0 = 1;
    while (t0 + 8 <= lmax) {
#pragma unroll
        for (int q = 0; q < 8; ++q) superstep(t0 + q, wCA[q], wCB[q]);
#pragma unroll
        for (int q = 0; q < 8; ++q) { wCA[q] = __expf(eNA[q]); wCB[q] = __expf(eNB[q]); }
#pragma unroll
        for (int q = 0; q < 8; ++q) {
            int ia = t0 + 15 + q; if (ia > lenA - 1) ia = lenA - 1;
            int ib = t0 + 15 + q; if (ib > lenB - 1) ib = lenB - 1;
            eNA[q] = emit[eA + (size_t)ia * Nn + lane];
            eNB[q] = emit[eB + (size_t)ib * Nn + lane];
        }
        t0 += 8;
    }
#pragma unroll
    for (int q = 0; q < 8; ++q)
        if (t0 + q < lmax) superstep(t0 + q, wCA[q], wCB[q]);

    // ---- logZ epilogues (per chain, at its own len) ----
    const float etv = etrans[lane];
    float eLA = emit[eA + (size_t)(lenA - 1) * Nn + lane];
    float eLB = emit[eB + (size_t)(lenB - 1) * Nn + lane];
    float zA = wave_sum(uuA * __expf(eLA + etv));
    float zB = wave_sum(uuB * __expf(eLB + etv));
    const float LN2 = 0.6931471805599453f;
    float lzA = __logf(zA) - (float)SA * LN2;
    float lzB = __logf(zB) - (float)SB * LN2;

    // ---- gold-path scores (fully out of the hot loop) ----
    const int* trA = target + (size_t)bA * Tn;
    const int* trB = target + (size_t)bB * Tn;
    float scA = 0.0f, scB = 0.0f;
#pragma unroll
    for (int k = 0; k < Tn / Nn; ++k) {
        int t = k * Nn + lane;
        int gA = trA[t], gB = trB[t];
        int pA = trA[t > 0 ? t - 1 : 0], pB = trB[t > 0 ? t - 1 : 0];
        if (t < lenA) {
            scA += emit[eA + (size_t)t * Nn + gA];
            if (t > 0) scA += trans[pA * Nn + gA];
        }
        if (t < lenB) {
            scB += emit[eB + (size_t)t * Nn + gB];
            if (t > 0) scB += trans[pB * Nn + gB];
        }
    }
    scA = wave_sum(scA);
    scB = wave_sum(scB);

    if (lane == 0) {
        float scoreA = scA + strans[trA[0]] + etrans[trA[lenA - 1]];
        float scoreB = scB + strans[trB[0]] + etrans[trB[lenB - 1]];
        atomicAdd(out, ((lzA - scoreA) + (lzB - scoreB)) * (1.0f / (float)Bn));
    }
}

extern "C" void kernel_launch(void* const* d_in, const int* in_sizes, int n_in,
                              void* d_out, int out_size, void* d_ws, size_t ws_size,
                              hipStream_t stream) {
    const float* emit   = (const float*)d_in[0];
    const int*   target = (const int*)d_in[1];
    const int*   mask   = (const int*)d_in[2];
    const float* trans  = (const float*)d_in[3];
    const float* strans = (const float*)d_in[4];
    const float* etrans = (const float*)d_in[5];
    float* out = (float*)d_out;

    hipMemsetAsync(out, 0, sizeof(float), stream);
    crf_dual<<<NB, Nn, 0, stream>>>(emit, target, mask, trans, strans, etrans, out);
}

// Round 5
// 247.265 us; speedup vs baseline: 1.9709x; 1.9709x over previous
//
#include <hip/hip_runtime.h>

#define Bn 512
#define Tn 1024
#define Nn 64
#define Kseg 8          // segments per sequence (grid = Bn*Kseg blocks)
#define BURN 16         // burn-in steps: direction converges ~0.35^16 ≈ 3e-8

typedef _Float16 h2 __attribute__((ext_vector_type(2)));
typedef _Float16 h8 __attribute__((ext_vector_type(8)));

#if __has_builtin(__builtin_amdgcn_fdot2)
__device__ __forceinline__ float fdot2f(h2 a, h2 b, float c) {
    return __builtin_amdgcn_fdot2(a, b, c, false);
}
#else
__device__ __forceinline__ float fdot2f(h2 a, h2 b, float c) {
    return fmaf((float)a[0], (float)b[0], fmaf((float)a[1], (float)b[1], c));
}
#endif

__device__ __forceinline__ float wave_sum(float v) {
#pragma unroll
    for (int off = 32; off >= 1; off >>= 1) v += __shfl_xor(v, off, 64);
    return v;
}

// One wave = one (batch, segment). Segment s covers steps t in [a_s, a_{s+1})
// of the forward recursion u_t = E^T diag(exp(emit_{t-1})) u_{t-1}.
// s>0 starts from u=1 and runs BURN warm-up steps (Birkhoff contraction makes
// the direction exact to fp32 by then); contribution log(sum u_end) - S*ln2
// - log(sum u_start) is scale-invariant and telescopes to logZ.
__global__ __launch_bounds__(64) void crf_seg(
    const float* __restrict__ emit,
    const int*   __restrict__ target,
    const int*   __restrict__ mask,
    const float* __restrict__ trans,
    const float* __restrict__ strans,
    const float* __restrict__ etrans,
    float*       __restrict__ out)
{
    __shared__ __align__(16) _Float16 pbuf[Nn];

    const int lane = threadIdx.x;
    const int b    = blockIdx.x & (Bn - 1);
    const int s    = blockIdx.x >> 9;          // 0..Kseg-1

    // E column j (j = lane) as fp16 pairs over i
    h2 E2[32];
#pragma unroll
    for (int m = 0; m < 32; ++m) {
        float x0 = trans[(2 * m) * Nn + lane];
        float x1 = trans[(2 * m + 1) * Nn + lane];
        h2 e; e[0] = (_Float16)__expf(x0); e[1] = (_Float16)__expf(x1);
        E2[m] = e;
    }

    // len = popcount of prefix mask
    const int* mrow = mask + (size_t)b * Tn;
    int lsum = 0;
#pragma unroll
    for (int k = 0; k < Tn / Nn; ++k) lsum += mrow[k * Nn + lane];
#pragma unroll
    for (int off = 32; off >= 1; off >>= 1) lsum += __shfl_xor(lsum, off, 64);
    const int len = lsum;                      // in [512, 1024]

    // segment bounds (identical arithmetic in every block of this b)
    const int a_s = (s * len) >> 3;            // Kseg = 8
    const int a_e = ((s + 1) * len) >> 3;      // s=7 -> len
    const int tb   = s ? (a_s - BURN) : 1;     // first executed step
    const int tend = a_e - 1;                  // last executed step
    const int rec_t = s ? a_s : -1;            // record point (never hits for s=0)

    const size_t ebase = (size_t)b * Tn * Nn;

    float uu = s ? 1.0f : __expf(strans[lane]);
    int   S  = 0;
    float L0 = 0.0f;

    // w pipeline: wC[q] = exp(emit row tb-1+q); eN = raw rows tb+7..tb+14
    float wC[8], eN[8];
#pragma unroll
    for (int q = 0; q < 8; ++q) wC[q] = emit[ebase + (size_t)(tb - 1 + q) * Nn + lane];
#pragma unroll
    for (int q = 0; q < 8; ++q) eN[q] = emit[ebase + (size_t)(tb + 7 + q) * Nn + lane];
#pragma unroll
    for (int q = 0; q < 8; ++q) wC[q] = __expf(wC[q]);

    auto step = [&](float w) {
        int bits = __builtin_amdgcn_readfirstlane(__float_as_int(uu));
        int mk   = 127 - ((bits >> 23) & 0xff);
        S += mk;
        float p = ldexpf(uu, mk) * w;          // p in (0, ~1300) -> fp16 safe
        pbuf[lane] = (_Float16)p;

        const h8* pb8 = (const h8*)pbuf;       // 8 broadcast b128 reads, in-order DS
        float a0 = 0.f, a1 = 0.f, a2 = 0.f, a3 = 0.f;
        float a4 = 0.f, a5 = 0.f, a6 = 0.f, a7 = 0.f;
#pragma unroll
        for (int r = 0; r < 8; r += 2) {
            h8 v0 = pb8[r], v1 = pb8[r + 1];
            a0 = fdot2f(__builtin_shufflevector(v0, v0, 0, 1), E2[4 * r + 0], a0);
            a1 = fdot2f(__builtin_shufflevector(v0, v0, 2, 3), E2[4 * r + 1], a1);
            a2 = fdot2f(__builtin_shufflevector(v0, v0, 4, 5), E2[4 * r + 2], a2);
            a3 = fdot2f(__builtin_shufflevector(v0, v0, 6, 7), E2[4 * r + 3], a3);
            a4 = fdot2f(__builtin_shufflevector(v1, v1, 0, 1), E2[4 * r + 4], a4);
            a5 = fdot2f(__builtin_shufflevector(v1, v1, 2, 3), E2[4 * r + 5], a5);
            a6 = fdot2f(__builtin_shufflevector(v1, v1, 4, 5), E2[4 * r + 6], a6);
            a7 = fdot2f(__builtin_shufflevector(v1, v1, 6, 7), E2[4 * r + 7], a7);
        }
        uu = ((a0 + a1) + (a2 + a3)) + ((a4 + a5) + (a6 + a7));
    };

    int t0 = tb;
    while (t0 + 8 <= tend + 1) {
#pragma unroll
        for (int q = 0; q < 8; ++q) step(wC[q]);
#pragma unroll
        for (int q = 0; q < 8; ++q) wC[q] = __expf(eN[q]);
#pragma unroll
        for (int q = 0; q < 8; ++q) {
            int idx = t0 + 15 + q; if (idx > tend - 1) idx = tend - 1;
            eN[q] = emit[ebase + (size_t)idx * Nn + lane];
        }
        t0 += 8;
        if (t0 == rec_t) {                    // burn-in done: u = c*v_{a_s-1}
            L0 = __logf(wave_sum(uu));
            S = 0;
        }
    }
#pragma unroll
    for (int q = 0; q < 8; ++q)
        if (t0 + q <= tend) step(wC[q]);

    // segment logZ contribution
    float lend;
    if (s == Kseg - 1) {
        float eL = emit[ebase + (size_t)(len - 1) * Nn + lane];
        lend = __logf(wave_sum(uu * __expf(eL + etrans[lane])));
    } else {
        lend = __logf(wave_sum(uu));
    }
    float contrib = lend - (float)S * 0.6931471805599453f - L0;

    // gold-path score for t in [a_s, a_e)  (s=0: [0, a_1))
    const int* trow = target + (size_t)b * Tn;
    const int t_sc = s ? a_s : 0;
    float sc = 0.0f;
#pragma unroll
    for (int k = 0; k < 3; ++k) {             // covers max range 129
        int t = t_sc + k * Nn + lane;
        if (t < a_e) {
            int g = trow[t];
            sc += emit[ebase + (size_t)t * Nn + g];
            if (t > 0) sc += trans[trow[t - 1] * Nn + g];
        }
    }
    sc = wave_sum(sc);

    if (lane == 0) {
        if (s == 0)        sc += strans[trow[0]];
        if (s == Kseg - 1) sc += etrans[trow[len - 1]];
        atomicAdd(out, (contrib - sc) * (1.0f / (float)Bn));
    }
}

extern "C" void kernel_launch(void* const* d_in, const int* in_sizes, int n_in,
                              void* d_out, int out_size, void* d_ws, size_t ws_size,
                              hipStream_t stream) {
    const float* emit   = (const float*)d_in[0];
    const int*   target = (const int*)d_in[1];
    const int*   mask   = (const int*)d_in[2];
    const float* trans  = (const float*)d_in[3];
    const float* strans = (const float*)d_in[4];
    const float* etrans = (const float*)d_in[5];
    float* out = (float*)d_out;

    hipMemsetAsync(out, 0, sizeof(float), stream);
    crf_seg<<<Bn * Kseg, Nn, 0, stream>>>(emit, target, mask, trans, strans, etrans, out);
}